// Round 1
// 248.853 us; speedup vs baseline: 1.0066x; 1.0066x over previous
//
#include <hip/hip_runtime.h>
#include <hip/hip_bf16.h>

constexpr int H  = 256;
constexpr int H2 = 128;
constexpr int N  = 1024;
constexpr int T  = 12;
constexpr int B  = 4;
constexpr int M  = B * N; // 4096 rows total

using short8 = __attribute__((ext_vector_type(8))) short;
using f32x4  = __attribute__((ext_vector_type(4))) float;

// fp32 -> bf16 bits, round-to-nearest-even
__device__ __forceinline__ unsigned short f2bf(float f) {
    union { float f; unsigned int u; } v; v.f = f;
    unsigned int u = v.u;
    u += 0x7FFFu + ((u >> 16) & 1u);
    return (unsigned short)(u >> 16);
}

// ---------------- k1: prep — bf16 casts + weight transposes + Wb fold -------
// xb[m][k]   = bf16(x)                       (M x H)
// W1T[n][k]  = bf16(n<256 ? W1o[k][n] : W1d[k][n-256])            (512 x 256)
// W2T[n][k]  = bf16(n<128 ? (W2o@Wb)[k][n] : W2d[k][n-128])       (256 x 256)
//   (Wb folded into the origin branch here: (W2o@Wb)[k][n] = sum_l W2o[k][l]*Wb[l][n])
// bias1[512] = [b1o|b1d], bias2[256] = [b2o@Wb | b2d]  (fp32)
__global__ void prep_kernel(const float* __restrict__ x,
                            const float* __restrict__ W1o, const float* __restrict__ W1d,
                            const float* __restrict__ b1o, const float* __restrict__ b1d,
                            const float* __restrict__ W2o, const float* __restrict__ b2o,
                            const float* __restrict__ W2d, const float* __restrict__ b2d,
                            const float* __restrict__ Wb,
                            unsigned short* __restrict__ xb,
                            unsigned short* __restrict__ W1T,
                            unsigned short* __restrict__ W2T,
                            float* __restrict__ bias1, float* __restrict__ bias2)
{
    const int NX  = M * H;        // 1048576
    const int NW1 = 512 * H;      // 131072
    const int NW2 = 256 * H;      // 65536
    const int TOT = NX + NW1 + NW2 + 512 + 256;
    for (int i = blockIdx.x * blockDim.x + threadIdx.x; i < TOT;
         i += gridDim.x * blockDim.x) {
        if (i < NX) {
            xb[i] = f2bf(x[i]);
        } else if (i < NX + NW1) {
            const int j = i - NX, n = j >> 8, k = j & 255;
            const float v = (n < 256) ? W1o[k * H + n] : W1d[k * H + (n - 256)];
            W1T[j] = f2bf(v);
        } else if (i < NX + NW1 + NW2) {
            const int j = i - NX - NW1, n = j >> 8, k = j & 255;
            float v;
            if (n < 128) {
                // fold Wb into origin W2: (W2o @ Wb)[k][n]
                float acc = 0.f;
#pragma unroll 8
                for (int l2 = 0; l2 < H2; ++l2)
                    acc = fmaf(W2o[k * H2 + l2], Wb[l2 * H2 + n], acc);
                v = acc;
            } else {
                v = W2d[k * H2 + (n - 128)];
            }
            W2T[j] = f2bf(v);
        } else if (i < NX + NW1 + NW2 + 512) {
            const int j = i - NX - NW1 - NW2;
            bias1[j] = (j < 256) ? b1o[j] : b1d[j - 256];
        } else {
            const int j = i - NX - NW1 - NW2 - 512;
            float v;
            if (j < 128) {
                float acc = 0.f;
#pragma unroll 8
                for (int l2 = 0; l2 < H2; ++l2)
                    acc = fmaf(b2o[l2], Wb[l2 * H2 + j], acc);
                v = acc;
            } else {
                v = b2d[j - 128];
            }
            bias2[j] = v;
        }
    }
}

// ---------------- MFMA 64x64 tile body, K=256, bf16 in / bf16 out -----------
// 4 waves; wave w owns output cols [16w,16w+16). Per K-chunk(32): 1 B-frag +
// 4 A-frag ds_read_b128 + 4 mfma. LDS rows padded to 40 shorts (80B) so all
// 16B reads stay aligned and bank groups are balanced.
template<bool RELU>
__device__ __forceinline__ void enc_body(
    const unsigned short* __restrict__ A, int lda,   // pre-offset to row0
    const unsigned short* __restrict__ Bt,           // pre-offset; ldb=256
    const float* __restrict__ bias,                  // pre-offset to col0
    unsigned short* __restrict__ C, int ldc)         // pre-offset to (row0,col0)
{
    __shared__ unsigned short Abuf[64 * 40];
    __shared__ unsigned short Bbuf[64 * 40];
    const int tid = threadIdx.x;
    const int w  = tid >> 6;
    const int l  = tid & 63;
    const int lr = tid >> 2;            // staging row 0..63
    const int lk = (tid & 3) * 8;       // staging k offset (shorts)

    uint4 aR = *(const uint4*)(A + (size_t)lr * lda + lk);
    uint4 bR = *(const uint4*)(Bt + (size_t)lr * 256 + lk);

    f32x4 z = {0.f, 0.f, 0.f, 0.f};
    f32x4 acc[4] = {z, z, z, z};

    for (int kc = 0; kc < 256; kc += 32) {
        if (kc) __syncthreads();
        *(uint4*)&Abuf[lr * 40 + lk] = aR;
        *(uint4*)&Bbuf[lr * 40 + lk] = bR;
        __syncthreads();
        if (kc + 32 < 256) {
            aR = *(const uint4*)(A + (size_t)lr * lda + kc + 32 + lk);
            bR = *(const uint4*)(Bt + (size_t)lr * 256 + kc + 32 + lk);
        }
        const int q8 = (l >> 4) * 8;
        const short8 bf = *(const short8*)&Bbuf[(w * 16 + (l & 15)) * 40 + q8];
#pragma unroll
        for (int it = 0; it < 4; ++it) {
            const short8 af = *(const short8*)&Abuf[(it * 16 + (l & 15)) * 40 + q8];
            acc[it] = __builtin_amdgcn_mfma_f32_16x16x32_bf16(af, bf, acc[it], 0, 0, 0);
        }
    }

    // epilogue: D col = lane&15, row = (lane>>4)*4 + reg  [m89/m91 verified]
    const int n  = w * 16 + (l & 15);
    const int r0 = (l >> 4) * 4;
    const float bn = bias[n];
#pragma unroll
    for (int it = 0; it < 4; ++it)
#pragma unroll
        for (int r = 0; r < 4; ++r) {
            float v = acc[it][r] + bn;
            if (RELU) v = fmaxf(v, 0.f);
            C[(size_t)(it * 16 + r0 + r) * ldc + n] = f2bf(v);
        }
}

// k2: h = relu(x @ [W1o|W1d] + bias1), bf16 out (M x 512). grid (8, 64)
__global__ __launch_bounds__(256) void enc1_kernel(
    const unsigned short* __restrict__ xb, const unsigned short* __restrict__ W1T,
    const float* __restrict__ bias1, unsigned short* __restrict__ h)
{
    const int bx = blockIdx.x, by = blockIdx.y;
    enc_body<true>(xb + (size_t)by * 64 * 256, 256,
                   W1T + (size_t)bx * 64 * 256,
                   bias1 + bx * 64,
                   h + (size_t)by * 64 * 512 + bx * 64, 512);
}

// k3: od = [oW | dd] = h_branch @ W2T + bias2, bf16 out (M x 256). grid (4, 64)
__global__ __launch_bounds__(256) void enc2_kernel(
    const unsigned short* __restrict__ h, const unsigned short* __restrict__ W2T,
    const float* __restrict__ bias2, unsigned short* __restrict__ od)
{
    const int bx = blockIdx.x, by = blockIdx.y;
    enc_body<false>(h + (size_t)by * 64 * 512 + (bx >> 1) * 256, 512,
                    W2T + (size_t)bx * 64 * 256,
                    bias2 + bx * 64,
                    od + (size_t)by * 64 * 256 + bx * 64, 256);
}

// ---------------- k4: scores (MFMA) + fused horizon expansion ---------------
// 64x64 score tile, grid (16,16,4) = 1024 blocks. K = 128 (4 chunks).
// OPERAND SWAP vs previous version: dd rows feed the A operand, oW rows feed
// the B operand, so D[m=j][n=i] = sum_k dd[j][k]*oW[i][k] = scores[i][j].
// The reg dimension (m) now walks 4 CONSECUTIVE j -> each (t,it) writes one
// global_store_dwordx4 instead of 4 scalar dword stores (48 vs 192 stores
// per thread; wave-store = 16 rows x 64B contiguous, x4 fewer store instrs).
__global__ __launch_bounds__(256) void k3_kernel(
    const unsigned short* __restrict__ od,
    const float* __restrict__ bbp, const float* __restrict__ wh,
    const float* __restrict__ bh, float* __restrict__ out)
{
    __shared__ unsigned short Obuf[64 * 40];   // oW rows (i)  -> B operand
    __shared__ unsigned short Dbuf[64 * 40];   // dd rows (j)  -> A operand
    const int tid = threadIdx.x;
    const int w  = tid >> 6;
    const int l  = tid & 63;
    const int lr = tid >> 2;
    const int lk = (tid & 3) * 8;
    const int b  = blockIdx.z;
    const int i0 = blockIdx.y * 64;
    const int j0 = blockIdx.x * 64;
    const unsigned short* Ob = od + ((size_t)b * N + i0) * 256;        // oW rows
    const unsigned short* Db = od + ((size_t)b * N + j0) * 256 + 128;  // dd rows

    uint4 oR = *(const uint4*)(Ob + (size_t)lr * 256 + lk);
    uint4 dR = *(const uint4*)(Db + (size_t)lr * 256 + lk);

    f32x4 z = {0.f, 0.f, 0.f, 0.f};
    f32x4 acc[4] = {z, z, z, z};

    for (int kc = 0; kc < H2; kc += 32) {
        if (kc) __syncthreads();
        *(uint4*)&Obuf[lr * 40 + lk] = oR;
        *(uint4*)&Dbuf[lr * 40 + lk] = dR;
        __syncthreads();
        if (kc + 32 < H2) {
            oR = *(const uint4*)(Ob + (size_t)lr * 256 + kc + 32 + lk);
            dR = *(const uint4*)(Db + (size_t)lr * 256 + kc + 32 + lk);
        }
        const int q8 = (l >> 4) * 8;
        // B operand: oW rows -> i on the lane dimension
        const short8 bf = *(const short8*)&Obuf[(w * 16 + (l & 15)) * 40 + q8];
#pragma unroll
        for (int it = 0; it < 4; ++it) {
            // A operand: dd rows -> j on the reg dimension
            const short8 af = *(const short8*)&Dbuf[(it * 16 + (l & 15)) * 40 + q8];
            acc[it] = __builtin_amdgcn_mfma_f32_16x16x32_bf16(af, bf, acc[it], 0, 0, 0);
        }
    }

    const float bbv = bbp[0];
    float s[4][4];   // s[it][r]: score at row iRow, col j0 + it*16 + r0 + r
#pragma unroll
    for (int it = 0; it < 4; ++it)
#pragma unroll
        for (int r = 0; r < 4; ++r) s[it][r] = acc[it][r] + bbv;

    const int iRow = i0 + w * 16 + (l & 15);   // output row i (lane dim)
    const int r0   = (l >> 4) * 4;             // j sub-offset (reg dim)
    // out[((b*T+t)*N + i)*N + j]; per (t,it): one 16B store of 4 consecutive j
#pragma unroll
    for (int t = 0; t < T; ++t) {
        const float wt = wh[t], bt = bh[t];
        float* ob = out + ((size_t)(b * T + t) * N + iRow) * N + j0 + r0;
#pragma unroll
        for (int it = 0; it < 4; ++it) {
            f32x4 v;
#pragma unroll
            for (int r = 0; r < 4; ++r)
                v[r] = fmaxf(fmaf(s[it][r], wt, bt), 0.f);
            *(f32x4*)(ob + it * 16) = v;
        }
    }
}

extern "C" void kernel_launch(void* const* d_in, const int* in_sizes, int n_in,
                              void* d_out, int out_size, void* d_ws, size_t ws_size,
                              hipStream_t stream) {
    const float* x   = (const float*)d_in[0];
    const float* W1o = (const float*)d_in[1];
    const float* b1o = (const float*)d_in[2];
    const float* W2o = (const float*)d_in[3];
    const float* b2o = (const float*)d_in[4];
    const float* W1d = (const float*)d_in[5];
    const float* b1d = (const float*)d_in[6];
    const float* W2d = (const float*)d_in[7];
    const float* b2d = (const float*)d_in[8];
    const float* Wb  = (const float*)d_in[9];
    const float* bb  = (const float*)d_in[10];
    const float* wh  = (const float*)d_in[11];
    const float* bh  = (const float*)d_in[12];
    float* out = (float*)d_out;

    // workspace layout: fp32 first, then bf16 (all 16B-aligned)
    float* bias1 = (float*)d_ws;                            // 512
    float* bias2 = bias1 + 512;                             // 256
    unsigned short* xb  = (unsigned short*)(bias2 + 256);   // M*256
    unsigned short* W1T = xb + (size_t)M * H;               // 512*256
    unsigned short* W2T = W1T + 512 * H;                    // 256*256
    unsigned short* h   = W2T + 256 * H;                    // M*512
    unsigned short* od  = h + (size_t)M * 512;              // M*256 = [oW|dd]

    prep_kernel<<<1024, 256, 0, stream>>>(x, W1o, W1d, b1o, b1d,
                                          W2o, b2o, W2d, b2d, Wb,
                                          xb, W1T, W2T, bias1, bias2);

    enc1_kernel<<<dim3(8, M / 64), 256, 0, stream>>>(xb, W1T, bias1, h);

    enc2_kernel<<<dim3(4, M / 64), 256, 0, stream>>>(h, W2T, bias2, od);

    k3_kernel<<<dim3(N / 64, N / 64, B), 256, 0, stream>>>(od, bb, wh, bh, out);
}